// Round 1
// baseline (649.475 us; speedup 1.0000x reference)
//
#include <hip/hip_runtime.h>

// ---------------------------------------------------------------------------
// GCN with edge sampling, fp32. Structure per launch:
//   build CSR by dst (hist -> scan -> fill)
//   pass1: conv0(relu) conv1(relu) conv2 -> tmp_z
//   mask = sigmoid(tmp_z[src].tmp_z[dst]) > edge_rand ; deg_mask
//   pass2: conv0'(relu) conv1'(relu) conv2(full) -> out
// conv: h = A@W ; out[v] = dinv[v]*(sum_e h[src]*coef[e] + h[v]*dinv[v]) + b
// ---------------------------------------------------------------------------

__global__ void k_hist(const int* __restrict__ dst, int* __restrict__ indeg, int E) {
    int e = blockIdx.x * blockDim.x + threadIdx.x;
    if (e < E) atomicAdd(&indeg[dst[e]], 1);
}

__global__ void k_scan1(const int* __restrict__ in, int* __restrict__ out,
                        int* __restrict__ bsums, int N) {
    __shared__ int tmp[256];
    int i = blockIdx.x * 256 + threadIdx.x;
    int v = (i < N) ? in[i] : 0;
    tmp[threadIdx.x] = v;
    __syncthreads();
    for (int off = 1; off < 256; off <<= 1) {
        int t = (threadIdx.x >= off) ? tmp[threadIdx.x - off] : 0;
        __syncthreads();
        tmp[threadIdx.x] += t;
        __syncthreads();
    }
    if (i < N) out[i] = tmp[threadIdx.x] - v;   // exclusive
    if (threadIdx.x == 255) bsums[blockIdx.x] = tmp[255];
}

__global__ void k_scan2(int* __restrict__ bsums, int nb) {
    __shared__ int tmp[256];
    int v = (threadIdx.x < nb) ? bsums[threadIdx.x] : 0;
    tmp[threadIdx.x] = v;
    __syncthreads();
    for (int off = 1; off < 256; off <<= 1) {
        int t = (threadIdx.x >= off) ? tmp[threadIdx.x - off] : 0;
        __syncthreads();
        tmp[threadIdx.x] += t;
        __syncthreads();
    }
    if (threadIdx.x < nb) bsums[threadIdx.x] = tmp[threadIdx.x] - v;  // exclusive
}

__global__ void k_scan3(int* __restrict__ out, const int* __restrict__ bsums, int N, int E) {
    int i = blockIdx.x * 256 + threadIdx.x;
    if (i < N) out[i] += bsums[blockIdx.x];
    if (i == 0) out[N] = E;
}

__global__ void k_fill(const int* __restrict__ src, const int* __restrict__ dst,
                       const int* __restrict__ csr_off, int* __restrict__ cursor,
                       int* __restrict__ csr_src, int* __restrict__ csr_eid, int E) {
    int e = blockIdx.x * blockDim.x + threadIdx.x;
    if (e < E) {
        int d = dst[e];
        int pos = csr_off[d] + atomicAdd(&cursor[d], 1);
        csr_src[pos] = src[e];
        csr_eid[pos] = e;
    }
}

__global__ void k_dinv(const int* __restrict__ deg, float* __restrict__ dinv, int N) {
    int i = blockIdx.x * blockDim.x + threadIdx.x;
    if (i < N) dinv[i] = 1.0f / sqrtf((float)deg[i] + 1.0f);
}

__global__ void k_coef_full(const int* __restrict__ csr_src, const float* __restrict__ dinv,
                            float* __restrict__ coef, int E) {
    int i = blockIdx.x * blockDim.x + threadIdx.x;
    if (i < E) coef[i] = dinv[csr_src[i]];
}

__global__ void k_coef_mask(const int* __restrict__ csr_src, const int* __restrict__ csr_eid,
                            const float* __restrict__ dinv, const float* __restrict__ mask,
                            float* __restrict__ coef, int E) {
    int i = blockIdx.x * blockDim.x + threadIdx.x;
    if (i < E) coef[i] = dinv[csr_src[i]] * mask[csr_eid[i]];
}

// edge dot-product over 64 features, 16 lanes per edge
__global__ __launch_bounds__(256) void k_mask(const float* __restrict__ tz,
                                              const int* __restrict__ src,
                                              const int* __restrict__ dstv,
                                              const float* __restrict__ er,
                                              float* __restrict__ mask,
                                              int* __restrict__ degm, int E) {
    int gid = blockIdx.x * 256 + threadIdx.x;
    int e = gid >> 4;
    int l = gid & 15;
    if (e >= E) return;
    int s = src[e], d = dstv[e];
    const float4 a = *(const float4*)&tz[s * 64 + l * 4];
    const float4 b = *(const float4*)&tz[d * 64 + l * 4];
    float p = a.x * b.x + a.y * b.y + a.z * b.z + a.w * b.w;
    p += __shfl_xor(p, 1, 16);
    p += __shfl_xor(p, 2, 16);
    p += __shfl_xor(p, 4, 16);
    p += __shfl_xor(p, 8, 16);
    if (l == 0) {
        float sg = 1.0f / (1.0f + expf(-p));
        float m = (sg > er[e]) ? 1.0f : 0.0f;
        mask[e] = m;
        if (m != 0.0f) atomicAdd(&degm[d], 1);
    }
}

// C[N][OUTC] = A[N][128] x W[128][OUTC], fp32, 128-row tiles
template <int OUTC>
__global__ __launch_bounds__(256) void k_gemm(const float* __restrict__ A,
                                              const float* __restrict__ W,
                                              float* __restrict__ Cout, int N) {
    constexpr int TN = OUTC / 16;  // 8 or 4 cols per thread
    __shared__ float As[16][136];       // [k][row]
    __shared__ float Ws[16][OUTC + 8];  // [k][col]
    const int tid = threadIdx.x;
    const int tx = tid & 15;
    const int ty = tid >> 4;
    const int r0 = blockIdx.x * 128;

    float acc[8][TN];
#pragma unroll
    for (int i = 0; i < 8; i++)
#pragma unroll
        for (int j = 0; j < TN; j++) acc[i][j] = 0.0f;

    for (int k0 = 0; k0 < 128; k0 += 16) {
        __syncthreads();
#pragma unroll
        for (int l = 0; l < 2; ++l) {
            int idx = tid + l * 256;          // 0..511
            int row = idx >> 2;               // 0..127
            int c4 = idx & 3;                 // 0..3
            int gr = r0 + row;
            if (gr >= N) gr = N - 1;
            const float4 vv = *(const float4*)&A[(size_t)gr * 128 + k0 + c4 * 4];
            As[c4 * 4 + 0][row] = vv.x;
            As[c4 * 4 + 1][row] = vv.y;
            As[c4 * 4 + 2][row] = vv.z;
            As[c4 * 4 + 3][row] = vv.w;
        }
#pragma unroll
        for (int l = 0; l < (16 * OUTC / 4) / 256; ++l) {
            int idx = tid + l * 256;
            int row = idx / (OUTC / 4);
            int c4 = idx % (OUTC / 4);
            const float4 vv = *(const float4*)&W[(k0 + row) * OUTC + c4 * 4];
            *(float4*)&Ws[row][c4 * 4] = vv;
        }
        __syncthreads();
#pragma unroll
        for (int kk = 0; kk < 16; ++kk) {
            float a[8], b[TN];
#pragma unroll
            for (int i = 0; i < 8; i++) a[i] = As[kk][ty * 8 + i];
#pragma unroll
            for (int j = 0; j < TN; j++) b[j] = Ws[kk][tx * TN + j];
#pragma unroll
            for (int i = 0; i < 8; i++)
#pragma unroll
                for (int j = 0; j < TN; j++) acc[i][j] = fmaf(a[i], b[j], acc[i][j]);
        }
    }
#pragma unroll
    for (int i = 0; i < 8; i++) {
        int r = r0 + ty * 8 + i;
        if (r < N) {
#pragma unroll
            for (int j = 0; j < TN; j += 4) {
                float4 vv = make_float4(acc[i][j], acc[i][j + 1], acc[i][j + 2], acc[i][j + 3]);
                *(float4*)&Cout[(size_t)r * OUTC + tx * TN + j] = vv;
            }
        }
    }
}

// per-node gather aggregation: block = node, thread = feature
template <int C, bool RELU>
__global__ __launch_bounds__(C) void k_agg(const float* __restrict__ h,
                                           const int* __restrict__ csr_off,
                                           const int* __restrict__ csr_src,
                                           const float* __restrict__ coef,
                                           const float* __restrict__ dinv,
                                           const float* __restrict__ bias,
                                           float* __restrict__ out, int N) {
    __shared__ int s_src[128];
    __shared__ float s_w[128];
    const int v = blockIdx.x;
    const int f = threadIdx.x;
    const int e0 = csr_off[v];
    const int e1 = csr_off[v + 1];
    float acc = 0.0f;
    for (int base = e0; base < e1; base += 128) {
        int nchunk = min(128, e1 - base);
        __syncthreads();
        for (int j = f; j < nchunk; j += C) {
            s_src[j] = csr_src[base + j];
            s_w[j] = coef[base + j];
        }
        __syncthreads();
        int j = 0;
        for (; j + 3 < nchunk; j += 4) {
            float h0 = h[s_src[j + 0] * C + f];
            float h1 = h[s_src[j + 1] * C + f];
            float h2 = h[s_src[j + 2] * C + f];
            float h3 = h[s_src[j + 3] * C + f];
            acc = fmaf(h0, s_w[j + 0], acc);
            acc = fmaf(h1, s_w[j + 1], acc);
            acc = fmaf(h2, s_w[j + 2], acc);
            acc = fmaf(h3, s_w[j + 3], acc);
        }
        for (; j < nchunk; ++j) acc = fmaf(h[s_src[j] * C + f], s_w[j], acc);
    }
    float dv = dinv[v];
    float hv = h[v * C + f];
    float o = dv * (acc + hv * dv) + bias[f];
    if (RELU) o = fmaxf(o, 0.0f);
    out[v * C + f] = o;
}

extern "C" void kernel_launch(void* const* d_in, const int* in_sizes, int n_in,
                              void* d_out, int out_size, void* d_ws, size_t ws_size,
                              hipStream_t stream) {
    const float* x  = (const float*)d_in[0];
    const int*   ei = (const int*)d_in[1];
    const float* er = (const float*)d_in[2];
    const float* w0 = (const float*)d_in[3];
    const float* b0 = (const float*)d_in[4];
    const float* w1 = (const float*)d_in[5];
    const float* b1 = (const float*)d_in[6];
    const float* w2 = (const float*)d_in[7];
    const float* b2 = (const float*)d_in[8];
    const int N = in_sizes[0] / 128;
    const int E = in_sizes[2];
    const int* src  = ei;
    const int* dstv = ei + E;
    float* out = (float*)d_out;

    // workspace carve
    char* p = (char*)d_ws;
    auto alloc = [&](size_t bytes) {
        char* r = p;
        p += (bytes + 255) & ~(size_t)255;
        return r;
    };
    int* indeg     = (int*)alloc((size_t)N * 4);
    int* cursor    = (int*)alloc((size_t)N * 4);
    int* degm      = (int*)alloc((size_t)N * 4);
    int* csr_off   = (int*)alloc((size_t)(N + 1) * 4);
    int* bsums     = (int*)alloc(1024);
    int* csr_src   = (int*)alloc((size_t)E * 4);
    int* csr_eid   = (int*)alloc((size_t)E * 4);
    float* coefF   = (float*)alloc((size_t)E * 4);
    float* coefM   = (float*)alloc((size_t)E * 4);
    float* maskA   = (float*)alloc((size_t)E * 4);
    float* dinvF   = (float*)alloc((size_t)N * 4);
    float* dinvM   = (float*)alloc((size_t)N * 4);
    float* wk1     = (float*)alloc((size_t)N * 128 * 4);
    float* wk2     = (float*)alloc((size_t)N * 128 * 4);
    float* tz      = (float*)alloc((size_t)N * 64 * 4);

    hipMemsetAsync(indeg, 0, (size_t)N * 4, stream);
    hipMemsetAsync(cursor, 0, (size_t)N * 4, stream);
    hipMemsetAsync(degm, 0, (size_t)N * 4, stream);

    const int TB = 256;
    const int ebk = (E + TB - 1) / TB;
    const int nbk = (N + TB - 1) / TB;
    const int nb = (N + 255) / 256;

    // CSR build
    k_hist<<<ebk, TB, 0, stream>>>(dstv, indeg, E);
    k_scan1<<<nb, 256, 0, stream>>>(indeg, csr_off, bsums, N);
    k_scan2<<<1, 256, 0, stream>>>(bsums, nb);
    k_scan3<<<nb, 256, 0, stream>>>(csr_off, bsums, N, E);
    k_fill<<<ebk, TB, 0, stream>>>(src, dstv, csr_off, cursor, csr_src, csr_eid, E);
    k_dinv<<<nbk, TB, 0, stream>>>(indeg, dinvF, N);
    k_coef_full<<<ebk, TB, 0, stream>>>(csr_src, dinvF, coefF, E);

    const int gb = (N + 127) / 128;

    // pass 1 (full graph)
    k_gemm<128><<<gb, 256, 0, stream>>>(x, w0, wk2, N);
    k_agg<128, true><<<N, 128, 0, stream>>>(wk2, csr_off, csr_src, coefF, dinvF, b0, wk1, N);
    k_gemm<128><<<gb, 256, 0, stream>>>(wk1, w1, wk2, N);
    k_agg<128, true><<<N, 128, 0, stream>>>(wk2, csr_off, csr_src, coefF, dinvF, b1, wk1, N);
    k_gemm<64><<<gb, 256, 0, stream>>>(wk1, w2, wk2, N);
    k_agg<64, false><<<N, 64, 0, stream>>>(wk2, csr_off, csr_src, coefF, dinvF, b2, tz, N);

    // edge sampling
    k_mask<<<(int)(((size_t)E * 16 + 255) / 256), 256, 0, stream>>>(tz, src, dstv, er, maskA, degm, E);
    k_dinv<<<nbk, TB, 0, stream>>>(degm, dinvM, N);
    k_coef_mask<<<ebk, TB, 0, stream>>>(csr_src, csr_eid, dinvM, maskA, coefM, E);

    // pass 2 (sampled for layers 0/1, full for layer 2)
    k_gemm<128><<<gb, 256, 0, stream>>>(x, w0, wk2, N);
    k_agg<128, true><<<N, 128, 0, stream>>>(wk2, csr_off, csr_src, coefM, dinvM, b0, wk1, N);
    k_gemm<128><<<gb, 256, 0, stream>>>(wk1, w1, wk2, N);
    k_agg<128, true><<<N, 128, 0, stream>>>(wk2, csr_off, csr_src, coefM, dinvM, b1, wk1, N);
    k_gemm<64><<<gb, 256, 0, stream>>>(wk1, w2, wk2, N);
    k_agg<64, false><<<N, 64, 0, stream>>>(wk2, csr_off, csr_src, coefF, dinvF, b2, out, N);
}

// Round 2
// 615.015 us; speedup vs baseline: 1.0560x; 1.0560x over previous
//
#include <hip/hip_runtime.h>

// ---------------------------------------------------------------------------
// GCN with edge sampling, fp32.
//   build CSR by dst (hist -> scan -> fill packed int2(src,eid))
//   h0 = x@w0 computed ONCE, reused by both passes
//   pass1: agg(h0,coefF) relu -> gemm w1 -> agg relu -> gemm w2 -> agg64 -> tz
//   mask = sigmoid(tz[src].tz[dst]) > er ; degm
//   pass2: agg(h0,coefM) relu -> gemm w1 -> agg relu -> gemm w2 -> agg64(full) -> out
// conv: out[v] = dinv[v]*(sum_e h[src]*coef[e] + h[v]*dinv[v]) + b
// ---------------------------------------------------------------------------

__global__ void k_hist(const int* __restrict__ dst, int* __restrict__ indeg, int E) {
    int e = blockIdx.x * blockDim.x + threadIdx.x;
    if (e < E) atomicAdd(&indeg[dst[e]], 1);
}

__global__ void k_scan1(const int* __restrict__ in, int* __restrict__ out,
                        int* __restrict__ bsums, int N) {
    __shared__ int tmp[256];
    int i = blockIdx.x * 256 + threadIdx.x;
    int v = (i < N) ? in[i] : 0;
    tmp[threadIdx.x] = v;
    __syncthreads();
    for (int off = 1; off < 256; off <<= 1) {
        int t = (threadIdx.x >= off) ? tmp[threadIdx.x - off] : 0;
        __syncthreads();
        tmp[threadIdx.x] += t;
        __syncthreads();
    }
    if (i < N) out[i] = tmp[threadIdx.x] - v;   // exclusive
    if (threadIdx.x == 255) bsums[blockIdx.x] = tmp[255];
}

__global__ void k_scan2(int* __restrict__ bsums, int nb) {
    __shared__ int tmp[256];
    int v = (threadIdx.x < nb) ? bsums[threadIdx.x] : 0;
    tmp[threadIdx.x] = v;
    __syncthreads();
    for (int off = 1; off < 256; off <<= 1) {
        int t = (threadIdx.x >= off) ? tmp[threadIdx.x - off] : 0;
        __syncthreads();
        tmp[threadIdx.x] += t;
        __syncthreads();
    }
    if (threadIdx.x < nb) bsums[threadIdx.x] = tmp[threadIdx.x] - v;  // exclusive
}

__global__ void k_scan3(int* __restrict__ out, const int* __restrict__ bsums, int N, int E) {
    int i = blockIdx.x * 256 + threadIdx.x;
    if (i < N) out[i] += bsums[blockIdx.x];
    if (i == 0) out[N] = E;
}

__global__ void k_fill(const int* __restrict__ src, const int* __restrict__ dst,
                       const int* __restrict__ csr_off, int* __restrict__ cursor,
                       int2* __restrict__ csr_se, int E) {
    int e = blockIdx.x * blockDim.x + threadIdx.x;
    if (e < E) {
        int d = dst[e];
        int pos = csr_off[d] + atomicAdd(&cursor[d], 1);
        csr_se[pos] = make_int2(src[e], e);
    }
}

__global__ void k_dinv(const int* __restrict__ deg, float* __restrict__ dinv, int N) {
    int i = blockIdx.x * blockDim.x + threadIdx.x;
    if (i < N) dinv[i] = 1.0f / sqrtf((float)deg[i] + 1.0f);
}

__global__ void k_coef_full(const int2* __restrict__ csr_se, const float* __restrict__ dinv,
                            float* __restrict__ coef, int E) {
    int i = blockIdx.x * blockDim.x + threadIdx.x;
    if (i < E) coef[i] = dinv[csr_se[i].x];
}

__global__ void k_coef_mask(const int2* __restrict__ csr_se, const float* __restrict__ dinv,
                            const float* __restrict__ mask, float* __restrict__ coef, int E) {
    int i = blockIdx.x * blockDim.x + threadIdx.x;
    if (i < E) {
        int2 se = csr_se[i];
        coef[i] = dinv[se.x] * mask[se.y];
    }
}

// edge dot-product over 64 features, 16 lanes per edge
__global__ __launch_bounds__(256) void k_mask(const float* __restrict__ tz,
                                              const int* __restrict__ src,
                                              const int* __restrict__ dstv,
                                              const float* __restrict__ er,
                                              float* __restrict__ mask,
                                              int* __restrict__ degm, int E) {
    int gid = blockIdx.x * 256 + threadIdx.x;
    int e = gid >> 4;
    int l = gid & 15;
    if (e >= E) return;
    int s = src[e], d = dstv[e];
    const float4 a = *(const float4*)&tz[(size_t)s * 64 + l * 4];
    const float4 b = *(const float4*)&tz[(size_t)d * 64 + l * 4];
    float p = a.x * b.x + a.y * b.y + a.z * b.z + a.w * b.w;
    p += __shfl_xor(p, 1, 16);
    p += __shfl_xor(p, 2, 16);
    p += __shfl_xor(p, 4, 16);
    p += __shfl_xor(p, 8, 16);
    if (l == 0) {
        float sg = 1.0f / (1.0f + expf(-p));
        float m = (sg > er[e]) ? 1.0f : 0.0f;
        mask[e] = m;
        if (m != 0.0f) atomicAdd(&degm[d], 1);
    }
}

// C[N][OUTC] = A[N][128] x W[128][OUTC], fp32, 128-row tiles
template <int OUTC>
__global__ __launch_bounds__(256) void k_gemm(const float* __restrict__ A,
                                              const float* __restrict__ W,
                                              float* __restrict__ Cout, int N) {
    constexpr int TN = OUTC / 16;  // 8 or 4 cols per thread
    __shared__ float As[16][136];       // [k][row]
    __shared__ float Ws[16][OUTC + 8];  // [k][col]
    const int tid = threadIdx.x;
    const int tx = tid & 15;
    const int ty = tid >> 4;
    const int r0 = blockIdx.x * 128;

    float acc[8][TN];
#pragma unroll
    for (int i = 0; i < 8; i++)
#pragma unroll
        for (int j = 0; j < TN; j++) acc[i][j] = 0.0f;

    for (int k0 = 0; k0 < 128; k0 += 16) {
        __syncthreads();
#pragma unroll
        for (int l = 0; l < 2; ++l) {
            int idx = tid + l * 256;          // 0..511
            int row = idx >> 2;               // 0..127
            int c4 = idx & 3;                 // 0..3
            int gr = r0 + row;
            if (gr >= N) gr = N - 1;
            const float4 vv = *(const float4*)&A[(size_t)gr * 128 + k0 + c4 * 4];
            As[c4 * 4 + 0][row] = vv.x;
            As[c4 * 4 + 1][row] = vv.y;
            As[c4 * 4 + 2][row] = vv.z;
            As[c4 * 4 + 3][row] = vv.w;
        }
#pragma unroll
        for (int l = 0; l < (16 * OUTC / 4) / 256; ++l) {
            int idx = tid + l * 256;
            int row = idx / (OUTC / 4);
            int c4 = idx % (OUTC / 4);
            const float4 vv = *(const float4*)&W[(k0 + row) * OUTC + c4 * 4];
            *(float4*)&Ws[row][c4 * 4] = vv;
        }
        __syncthreads();
#pragma unroll
        for (int kk = 0; kk < 16; ++kk) {
            float a[8], b[TN];
#pragma unroll
            for (int i = 0; i < 8; i++) a[i] = As[kk][ty * 8 + i];
#pragma unroll
            for (int j = 0; j < TN; j++) b[j] = Ws[kk][tx * TN + j];
#pragma unroll
            for (int i = 0; i < 8; i++)
#pragma unroll
                for (int j = 0; j < TN; j++) acc[i][j] = fmaf(a[i], b[j], acc[i][j]);
        }
    }
#pragma unroll
    for (int i = 0; i < 8; i++) {
        int r = r0 + ty * 8 + i;
        if (r < N) {
#pragma unroll
            for (int j = 0; j < TN; j += 4) {
                float4 vv = make_float4(acc[i][j], acc[i][j + 1], acc[i][j + 2], acc[i][j + 3]);
                *(float4*)&Cout[(size_t)r * OUTC + tx * TN + j] = vv;
            }
        }
    }
}

// C=128 aggregation: block=128 thr; 32 lanes (float4) x 4 edge slots, unroll 2
template <bool RELU>
__global__ __launch_bounds__(128) void k_agg128(const float* __restrict__ h,
                                                const int* __restrict__ csr_off,
                                                const int2* __restrict__ csr_se,
                                                const float* __restrict__ coef,
                                                const float* __restrict__ dinv,
                                                const float* __restrict__ bias,
                                                float* __restrict__ out, int N) {
    const int v = blockIdx.x;
    const int l = threadIdx.x & 31;
    const int s = threadIdx.x >> 5;  // 0..3
    const int e0 = csr_off[v];
    const int e1 = csr_off[v + 1];
    float4 acc = make_float4(0.f, 0.f, 0.f, 0.f);
    int i = e0 + s;
    for (; i + 4 < e1; i += 8) {
        int sa = csr_se[i].x;
        float wa = coef[i];
        int sb = csr_se[i + 4].x;
        float wb = coef[i + 4];
        float4 a = *(const float4*)&h[(size_t)sa * 128 + l * 4];
        float4 b = *(const float4*)&h[(size_t)sb * 128 + l * 4];
        acc.x = fmaf(a.x, wa, acc.x); acc.y = fmaf(a.y, wa, acc.y);
        acc.z = fmaf(a.z, wa, acc.z); acc.w = fmaf(a.w, wa, acc.w);
        acc.x = fmaf(b.x, wb, acc.x); acc.y = fmaf(b.y, wb, acc.y);
        acc.z = fmaf(b.z, wb, acc.z); acc.w = fmaf(b.w, wb, acc.w);
    }
    if (i < e1) {
        int sa = csr_se[i].x;
        float wa = coef[i];
        float4 a = *(const float4*)&h[(size_t)sa * 128 + l * 4];
        acc.x = fmaf(a.x, wa, acc.x); acc.y = fmaf(a.y, wa, acc.y);
        acc.z = fmaf(a.z, wa, acc.z); acc.w = fmaf(a.w, wa, acc.w);
    }
    __shared__ float4 red[4][32];
    red[s][l] = acc;
    __syncthreads();
    if (threadIdx.x < 32) {
        float4 r0 = red[0][l], r1 = red[1][l], r2 = red[2][l], r3 = red[3][l];
        float dv = dinv[v];
        float4 hv = *(const float4*)&h[(size_t)v * 128 + l * 4];
        float4 bb = *(const float4*)&bias[l * 4];
        float4 o;
        o.x = dv * ((r0.x + r1.x + r2.x + r3.x) + hv.x * dv) + bb.x;
        o.y = dv * ((r0.y + r1.y + r2.y + r3.y) + hv.y * dv) + bb.y;
        o.z = dv * ((r0.z + r1.z + r2.z + r3.z) + hv.z * dv) + bb.z;
        o.w = dv * ((r0.w + r1.w + r2.w + r3.w) + hv.w * dv) + bb.w;
        if (RELU) {
            o.x = fmaxf(o.x, 0.f); o.y = fmaxf(o.y, 0.f);
            o.z = fmaxf(o.z, 0.f); o.w = fmaxf(o.w, 0.f);
        }
        *(float4*)&out[(size_t)v * 128 + l * 4] = o;
    }
}

// C=64 aggregation: block=128 thr; 16 lanes (float4) x 8 edge slots, unroll 2
__global__ __launch_bounds__(128) void k_agg64(const float* __restrict__ h,
                                               const int* __restrict__ csr_off,
                                               const int2* __restrict__ csr_se,
                                               const float* __restrict__ coef,
                                               const float* __restrict__ dinv,
                                               const float* __restrict__ bias,
                                               float* __restrict__ out, int N) {
    const int v = blockIdx.x;
    const int l = threadIdx.x & 15;
    const int s = threadIdx.x >> 4;  // 0..7
    const int e0 = csr_off[v];
    const int e1 = csr_off[v + 1];
    float4 acc = make_float4(0.f, 0.f, 0.f, 0.f);
    int i = e0 + s;
    for (; i + 8 < e1; i += 16) {
        int sa = csr_se[i].x;
        float wa = coef[i];
        int sb = csr_se[i + 8].x;
        float wb = coef[i + 8];
        float4 a = *(const float4*)&h[(size_t)sa * 64 + l * 4];
        float4 b = *(const float4*)&h[(size_t)sb * 64 + l * 4];
        acc.x = fmaf(a.x, wa, acc.x); acc.y = fmaf(a.y, wa, acc.y);
        acc.z = fmaf(a.z, wa, acc.z); acc.w = fmaf(a.w, wa, acc.w);
        acc.x = fmaf(b.x, wb, acc.x); acc.y = fmaf(b.y, wb, acc.y);
        acc.z = fmaf(b.z, wb, acc.z); acc.w = fmaf(b.w, wb, acc.w);
    }
    if (i < e1) {
        int sa = csr_se[i].x;
        float wa = coef[i];
        float4 a = *(const float4*)&h[(size_t)sa * 64 + l * 4];
        acc.x = fmaf(a.x, wa, acc.x); acc.y = fmaf(a.y, wa, acc.y);
        acc.z = fmaf(a.z, wa, acc.z); acc.w = fmaf(a.w, wa, acc.w);
    }
    __shared__ float4 red[8][16];
    red[s][l] = acc;
    __syncthreads();
    if (threadIdx.x < 16) {
        float4 aa = make_float4(0.f, 0.f, 0.f, 0.f);
#pragma unroll
        for (int k = 0; k < 8; ++k) {
            float4 r = red[k][l];
            aa.x += r.x; aa.y += r.y; aa.z += r.z; aa.w += r.w;
        }
        float dv = dinv[v];
        float4 hv = *(const float4*)&h[(size_t)v * 64 + l * 4];
        float4 bb = *(const float4*)&bias[l * 4];
        float4 o;
        o.x = dv * (aa.x + hv.x * dv) + bb.x;
        o.y = dv * (aa.y + hv.y * dv) + bb.y;
        o.z = dv * (aa.z + hv.z * dv) + bb.z;
        o.w = dv * (aa.w + hv.w * dv) + bb.w;
        *(float4*)&out[(size_t)v * 64 + l * 4] = o;
    }
}

extern "C" void kernel_launch(void* const* d_in, const int* in_sizes, int n_in,
                              void* d_out, int out_size, void* d_ws, size_t ws_size,
                              hipStream_t stream) {
    const float* x  = (const float*)d_in[0];
    const int*   ei = (const int*)d_in[1];
    const float* er = (const float*)d_in[2];
    const float* w0 = (const float*)d_in[3];
    const float* b0 = (const float*)d_in[4];
    const float* w1 = (const float*)d_in[5];
    const float* b1 = (const float*)d_in[6];
    const float* w2 = (const float*)d_in[7];
    const float* b2 = (const float*)d_in[8];
    const int N = in_sizes[0] / 128;
    const int E = in_sizes[2];
    const int* src  = ei;
    const int* dstv = ei + E;
    float* out = (float*)d_out;

    // workspace carve
    char* p = (char*)d_ws;
    auto alloc = [&](size_t bytes) {
        char* r = p;
        p += (bytes + 255) & ~(size_t)255;
        return r;
    };
    int* indeg     = (int*)alloc((size_t)N * 4);
    int* cursor    = (int*)alloc((size_t)N * 4);
    int* degm      = (int*)alloc((size_t)N * 4);
    int* csr_off   = (int*)alloc((size_t)(N + 1) * 4);
    int* bsums     = (int*)alloc(1024);
    int2* csr_se   = (int2*)alloc((size_t)E * 8);
    float* coefF   = (float*)alloc((size_t)E * 4);
    float* coefM   = (float*)alloc((size_t)E * 4);
    float* maskA   = (float*)alloc((size_t)E * 4);
    float* dinvF   = (float*)alloc((size_t)N * 4);
    float* dinvM   = (float*)alloc((size_t)N * 4);
    float* hx      = (float*)alloc((size_t)N * 128 * 4);  // x@w0, reused
    float* wk1     = (float*)alloc((size_t)N * 128 * 4);
    float* wk2     = (float*)alloc((size_t)N * 128 * 4);
    float* tz      = (float*)alloc((size_t)N * 64 * 4);

    hipMemsetAsync(indeg, 0, (size_t)N * 4, stream);
    hipMemsetAsync(cursor, 0, (size_t)N * 4, stream);
    hipMemsetAsync(degm, 0, (size_t)N * 4, stream);

    const int TB = 256;
    const int ebk = (E + TB - 1) / TB;
    const int nbk = (N + TB - 1) / TB;
    const int nb = (N + 255) / 256;

    // CSR build
    k_hist<<<ebk, TB, 0, stream>>>(dstv, indeg, E);
    k_scan1<<<nb, 256, 0, stream>>>(indeg, csr_off, bsums, N);
    k_scan2<<<1, 256, 0, stream>>>(bsums, nb);
    k_scan3<<<nb, 256, 0, stream>>>(csr_off, bsums, N, E);
    k_fill<<<ebk, TB, 0, stream>>>(src, dstv, csr_off, cursor, csr_se, E);
    k_dinv<<<nbk, TB, 0, stream>>>(indeg, dinvF, N);
    k_coef_full<<<ebk, TB, 0, stream>>>(csr_se, dinvF, coefF, E);

    const int gb = (N + 127) / 128;

    // shared first GEMM
    k_gemm<128><<<gb, 256, 0, stream>>>(x, w0, hx, N);

    // pass 1 (full graph)
    k_agg128<true><<<N, 128, 0, stream>>>(hx, csr_off, csr_se, coefF, dinvF, b0, wk1, N);
    k_gemm<128><<<gb, 256, 0, stream>>>(wk1, w1, wk2, N);
    k_agg128<true><<<N, 128, 0, stream>>>(wk2, csr_off, csr_se, coefF, dinvF, b1, wk1, N);
    k_gemm<64><<<gb, 256, 0, stream>>>(wk1, w2, wk2, N);
    k_agg64<<<N, 128, 0, stream>>>(wk2, csr_off, csr_se, coefF, dinvF, b2, tz, N);

    // edge sampling
    k_mask<<<(int)(((size_t)E * 16 + 255) / 256), 256, 0, stream>>>(tz, src, dstv, er, maskA, degm, E);
    k_dinv<<<nbk, TB, 0, stream>>>(degm, dinvM, N);
    k_coef_mask<<<ebk, TB, 0, stream>>>(csr_se, dinvM, maskA, coefM, E);

    // pass 2 (sampled for layers 0/1, full for layer 2)
    k_agg128<true><<<N, 128, 0, stream>>>(hx, csr_off, csr_se, coefM, dinvM, b0, wk1, N);
    k_gemm<128><<<gb, 256, 0, stream>>>(wk1, w1, wk2, N);
    k_agg128<true><<<N, 128, 0, stream>>>(wk2, csr_off, csr_se, coefM, dinvM, b1, wk1, N);
    k_gemm<64><<<gb, 256, 0, stream>>>(wk1, w2, wk2, N);
    k_agg64<<<N, 128, 0, stream>>>(wk2, csr_off, csr_se, coefF, dinvF, b2, out, N);
}